// Round 4
// baseline (105.043 us; speedup 1.0000x reference)
//
#include <hip/hip_runtime.h>

// A5ExactScan: s_{t+1} = mul[x_t, s_t] over T=2048 per row (B=16384), s0=0.
// Radix-2 chain with [s][p]-layout 6-bit-packed pair table in LDS:
//   bitpos = s*21600 + p*6   (row stride 21600 bits = 675 words = 2700 B)
// Word offset/shift depend only on the token pair -> computed off-chain.
// On-chain per pair: v_mad_u32_u24 -> ds_read2_b32 -> v_alignbit_b32 -> v_and.
//
// KEY FIX vs prior round: __launch_bounds__(64, 1). With extern __shared__
// (size unknown at compile time) the backend assumed LDS=0, targeted 8
// waves/EU, and capped the kernel at ~32 VGPRs -> token prefetch spilled to
// scratch -> global-load latency exposed on the chain. Declaring 1 wave/EU
// restores the full register file (we run 1 block/CU anyway: 162KB LDS).

#define T_LEN 2048
#define NTOK 60
#define NPAIR (NTOK * NTOK)     // 3600
#define ROW_WORDS 675           // 3600*6/32
#define NWORDS (NTOK * ROW_WORDS)       // 40500
#define ALLOC_WORDS (NWORDS + 4)        // +pad: last entry reads word 40500
#define TAB_BYTES (ALLOC_WORDS * 4)     // 162016 B
#define BROWS 64

// ---------------- kernel A: build packed [s][p] table in global scratch ----
__global__ void a5_build_kernel(const int* __restrict__ mul,
                                uint32_t* __restrict__ packed) {
  const int w = blockIdx.x * 256 + threadIdx.x;
  if (w >= ALLOC_WORDS) return;
  if (w >= NWORDS) { packed[w] = 0; return; }
  const uint32_t r = (uint32_t)w / ROW_WORDS;        // state s of this row
  const uint32_t woff = (uint32_t)w - r * ROW_WORDS; // word within row
  const uint32_t bit0 = woff * 32u;
  const uint32_t e0 = bit0 / 6u;                     // first pair overlapping
  const uint32_t sh0 = bit0 - e0 * 6u;               // 0..5
  uint64_t acc = 0;
#pragma unroll
  for (int k = 0; k < 7; ++k) {
    const uint32_t e = e0 + k;
    if (e < NPAIR) {
      const uint32_t x1 = e % 60u;
      const uint32_t x2 = e / 60u;
      const uint32_t v =
          (uint32_t)mul[x2 * 60u + (uint32_t)mul[x1 * 60u + r]];
      acc |= (uint64_t)v << (6 * k);
    }
  }
  packed[w] = (uint32_t)(acc >> sh0);
}

// ---------------- kernel B: per-row radix-2 chain ---------------------------
__global__ __launch_bounds__(BROWS, 1) void a5_scan2_kernel(
    const int* __restrict__ ids, const uint32_t* __restrict__ packed,
    float* __restrict__ out) {
  extern __shared__ uint32_t tab[];  // ALLOC_WORDS u32
  const int lane = threadIdx.x;

  // Fill LDS table (162 KB; L2/L3-hot after first blocks).
  {
    const uint4* s4 = (const uint4*)packed;
    uint4* d4 = (uint4*)tab;
#pragma unroll 4
    for (int i = lane; i < ALLOC_WORDS / 4; i += BROWS) d4[i] = s4[i];
  }
  __syncthreads();

  const int row = blockIdx.x * BROWS + lane;
  const int4* rp = (const int4*)(ids + (size_t)row * T_LEN);
  const char* tb = (const char*)tab;

  uint32_t s = 0;  // state; s0 = identity id 0

  // Off-chain prep: token pair (X1 earlier, X2 later) -> byte word-offset + shift
#define PREP(J, X1, X2)                                        \
  do {                                                         \
    const uint32_t p6_ = (uint32_t)(X2)*360u + (uint32_t)(X1)*6u; \
    po[J] = (p6_ >> 5) << 2;                                   \
    shv[J] = p6_ & 31u;                                        \
  } while (0)

  // On-chain pair step: mad -> ds_read2 -> alignbit -> and.
#define PSTEP(J)                                               \
  do {                                                         \
    const uint32_t a_ = s * 2700u + po[J];                     \
    const uint32_t lo_ = *(const uint32_t*)(tb + a_);          \
    const uint32_t hi_ = *(const uint32_t*)(tb + a_ + 4);      \
    s = __builtin_amdgcn_alignbit(hi_, lo_, shv[J]) & 63u;     \
  } while (0)

  uint32_t po[8], shv[8];
  {  // prologue: first 16 tokens
    int4 c0 = rp[0], c1 = rp[1], c2 = rp[2], c3 = rp[3];
    PREP(0, c0.x, c0.y); PREP(1, c0.z, c0.w);
    PREP(2, c1.x, c1.y); PREP(3, c1.z, c1.w);
    PREP(4, c2.x, c2.y); PREP(5, c2.z, c2.w);
    PREP(6, c3.x, c3.y); PREP(7, c3.z, c3.w);
  }

  for (int t = 0; t < T_LEN; t += 16) {
    int4 n0, n1, n2, n3;
    const bool more = (t + 16) < T_LEN;
    if (more) {
      const int4* np = rp + (t >> 2) + 4;
      n0 = np[0]; n1 = np[1]; n2 = np[2]; n3 = np[3];
    }
    // 8 dependent pair steps (~1100 cy) hide the loads above.
    PSTEP(0); PSTEP(1); PSTEP(2); PSTEP(3);
    PSTEP(4); PSTEP(5); PSTEP(6); PSTEP(7);
    if (more) {
      PREP(0, n0.x, n0.y); PREP(1, n0.z, n0.w);
      PREP(2, n1.x, n1.y); PREP(3, n1.z, n1.w);
      PREP(4, n2.x, n2.y); PREP(5, n2.z, n2.w);
      PREP(6, n3.x, n3.y); PREP(7, n3.z, n3.w);
    }
  }
#undef PSTEP
#undef PREP

  // One-hot row write: 15 x float4 = 60 floats, fully overwrites output.
  float4* op = (float4*)(out + (size_t)row * NTOK);
#pragma unroll
  for (int j = 0; j < 15; ++j) {
    float4 v;
    v.x = ((uint32_t)(4 * j + 0) == s) ? 5.0f : 0.0f;
    v.y = ((uint32_t)(4 * j + 1) == s) ? 5.0f : 0.0f;
    v.z = ((uint32_t)(4 * j + 2) == s) ? 5.0f : 0.0f;
    v.w = ((uint32_t)(4 * j + 3) == s) ? 5.0f : 0.0f;
    op[j] = v;
  }
}

// ---------------- fallback: round-1 single-token chain ----------------------
__global__ __launch_bounds__(BROWS, 1) void a5_scan_kernel(
    const int* __restrict__ ids, const int* __restrict__ mul,
    float* __restrict__ out) {
  __shared__ uint32_t tab[NTOK * NTOK];
  const int lane = threadIdx.x;
  for (int i = lane; i < NTOK * NTOK; i += BROWS)
    tab[i] = ((uint32_t)mul[i]) << 2;
  __syncthreads();

  const int row = blockIdx.x * BROWS + lane;
  const int4* rp = (const int4*)(ids + (size_t)row * T_LEN);
  const char* tb = (const char*)tab;
  int4 c0 = rp[0], c1 = rp[1], c2 = rp[2], c3 = rp[3];
  uint32_t s4 = 0;
#define STEP(X)                                  \
  do {                                           \
    uint32_t base_ = (uint32_t)(X)*240u;         \
    s4 = *(const uint32_t*)(tb + base_ + s4);    \
  } while (0)
  for (int t = 0; t < T_LEN; t += 16) {
    int4 n0, n1, n2, n3;
    const bool more = (t + 16) < T_LEN;
    if (more) {
      const int4* np = rp + (t >> 2) + 4;
      n0 = np[0]; n1 = np[1]; n2 = np[2]; n3 = np[3];
    }
    STEP(c0.x); STEP(c0.y); STEP(c0.z); STEP(c0.w);
    STEP(c1.x); STEP(c1.y); STEP(c1.z); STEP(c1.w);
    STEP(c2.x); STEP(c2.y); STEP(c2.z); STEP(c2.w);
    STEP(c3.x); STEP(c3.y); STEP(c3.z); STEP(c3.w);
    if (more) { c0 = n0; c1 = n1; c2 = n2; c3 = n3; }
  }
#undef STEP
  const uint32_t s = s4 >> 2;
  float4* op = (float4*)(out + (size_t)row * NTOK);
#pragma unroll
  for (int j = 0; j < 15; ++j) {
    float4 v;
    v.x = ((uint32_t)(4 * j + 0) == s) ? 5.0f : 0.0f;
    v.y = ((uint32_t)(4 * j + 1) == s) ? 5.0f : 0.0f;
    v.z = ((uint32_t)(4 * j + 2) == s) ? 5.0f : 0.0f;
    v.w = ((uint32_t)(4 * j + 3) == s) ? 5.0f : 0.0f;
    op[j] = v;
  }
}

extern "C" void kernel_launch(void* const* d_in, const int* in_sizes, int n_in,
                              void* d_out, int out_size, void* d_ws,
                              size_t ws_size, hipStream_t stream) {
  const int* ids = (const int*)d_in[0];
  const int* mul = (const int*)d_in[1];
  float* out = (float*)d_out;
  const int B = in_sizes[0] / T_LEN;  // 16384
  const int grid = B / BROWS;         // 256 blocks

  if (ws_size >= (size_t)TAB_BYTES) {
    uint32_t* packed = (uint32_t*)d_ws;
    (void)hipFuncSetAttribute((const void*)a5_scan2_kernel,
                              hipFuncAttributeMaxDynamicSharedMemorySize,
                              TAB_BYTES);
    a5_build_kernel<<<(ALLOC_WORDS + 255) / 256, 256, 0, stream>>>(mul, packed);
    a5_scan2_kernel<<<grid, BROWS, TAB_BYTES, stream>>>(ids, packed, out);
  } else {
    a5_scan_kernel<<<grid, BROWS, 0, stream>>>(ids, mul, out);
  }
}

// Round 5
// 84.810 us; speedup vs baseline: 1.2386x; 1.2386x over previous
//
#include <hip/hip_runtime.h>

// A5ExactScan: s_{t+1} = mul[x_t, s_t] over T=2048 per row (B=16384), s0=0.
// Radix-2 chain, [s][p]-layout 6-bit-packed pair table in LDS:
//   bitpos = s*21600 + p*6  (row stride 2700 B). Word offset/shift depend only
//   on the token pair (off-chain). On-chain per pair:
//   v_mad_u32_u24 -> ds_read2_b32 -> v_alignbit_b32 -> v_and  (~135 cy).
//
// KEY FIX this round: amdgpu_waves_per_eu(1,1). __launch_bounds__(64,1) only
// sets the MIN waves/EU; the scheduler still pressure-limits toward 8 waves/EU
// (dynamic LDS assumed 0) -> ~20 VGPRs -> po/shv demoted to scratch -> a
// scratch load landed ON the chain every pair (~300 cy/pair observed).
// Clamping max waves/EU to 1 frees the full register file. Token pipeline is
// 2 blocks deep so the vmcnt wait is ~2 iterations (~2200 cy) after issue.

#define T_LEN 2048
#define NTOK 60
#define NPAIR (NTOK * NTOK)             // 3600
#define ROW_WORDS 675                   // 3600*6/32
#define NWORDS (NTOK * ROW_WORDS)       // 40500
#define ALLOC_WORDS (NWORDS + 4)        // pad: last entry reads word 40500
#define TAB_BYTES (ALLOC_WORDS * 4)     // 162016 B
#define BROWS 64

// ---------------- kernel A: build packed [s][p] table in global scratch ----
__global__ void a5_build_kernel(const int* __restrict__ mul,
                                uint32_t* __restrict__ packed) {
  const int w = blockIdx.x * 256 + threadIdx.x;
  if (w >= ALLOC_WORDS) return;
  if (w >= NWORDS) { packed[w] = 0; return; }
  const uint32_t r = (uint32_t)w / ROW_WORDS;        // state s of this row
  const uint32_t woff = (uint32_t)w - r * ROW_WORDS; // word within row
  const uint32_t bit0 = woff * 32u;
  const uint32_t e0 = bit0 / 6u;
  const uint32_t sh0 = bit0 - e0 * 6u;
  uint64_t acc = 0;
#pragma unroll
  for (int k = 0; k < 7; ++k) {
    const uint32_t e = e0 + k;
    if (e < NPAIR) {
      const uint32_t x1 = e % 60u;
      const uint32_t x2 = e / 60u;
      const uint32_t v =
          (uint32_t)mul[x2 * 60u + (uint32_t)mul[x1 * 60u + r]];
      acc |= (uint64_t)v << (6 * k);
    }
  }
  packed[w] = (uint32_t)(acc >> sh0);
}

// ---------------- kernel B: per-row radix-2 chain ---------------------------
__global__ __launch_bounds__(BROWS)
__attribute__((amdgpu_waves_per_eu(1, 1)))
void a5_scan2_kernel(const int* __restrict__ ids,
                     const uint32_t* __restrict__ packed,
                     float* __restrict__ out) {
  extern __shared__ uint32_t tab[];  // ALLOC_WORDS u32
  const int lane = threadIdx.x;

  // Fill LDS table (162 KB; L2/L3-hot after first blocks).
  {
    const uint4* s4 = (const uint4*)packed;
    uint4* d4 = (uint4*)tab;
#pragma unroll 4
    for (int i = lane; i < ALLOC_WORDS / 4; i += BROWS) d4[i] = s4[i];
  }
  __syncthreads();

  const int row = blockIdx.x * BROWS + lane;
  const int4* rp = (const int4*)(ids + (size_t)row * T_LEN);
  const char* tb = (const char*)tab;

  uint32_t s = 0;  // state; s0 = identity id 0
  uint32_t po[8], shv[8];

#define PREP(J, X1, X2)                                           \
  do {                                                            \
    const uint32_t p6_ = (uint32_t)(X2)*360u + (uint32_t)(X1)*6u; \
    po[J] = (p6_ >> 5) << 2;                                      \
    shv[J] = p6_ & 31u;                                           \
  } while (0)

#define PSTEP(J)                                                  \
  do {                                                            \
    const uint32_t a_ = s * 2700u + po[J];                        \
    const uint32_t lo_ = *(const uint32_t*)(tb + a_);             \
    const uint32_t hi_ = *(const uint32_t*)(tb + a_ + 4);         \
    s = __builtin_amdgcn_alignbit(hi_, lo_, shv[J]) & 63u;        \
  } while (0)

  // Prologue: pairs for block 0 in po/shv; tokens for block 1 in n0..n3.
  int4 n0, n1, n2, n3;
  {
    int4 c0 = rp[0], c1 = rp[1], c2 = rp[2], c3 = rp[3];
    PREP(0, c0.x, c0.y); PREP(1, c0.z, c0.w);
    PREP(2, c1.x, c1.y); PREP(3, c1.z, c1.w);
    PREP(4, c2.x, c2.y); PREP(5, c2.z, c2.w);
    PREP(6, c3.x, c3.y); PREP(7, c3.z, c3.w);
    n0 = rp[4]; n1 = rp[5]; n2 = rp[6]; n3 = rp[7];
  }

  // Main loop: body b consumes po/shv (block b), PREPs block b+1 from n,
  // and issues loads for block b+2 (waited ~2 iterations later).
  for (int b = 0; b <= 125; ++b) {
    const int4* mp = rp + (size_t)(b + 2) * 4;
    int4 m0 = mp[0], m1 = mp[1], m2 = mp[2], m3 = mp[3];
    __builtin_amdgcn_sched_barrier(0);  // keep load-issue above the chain
    PSTEP(0); PSTEP(1); PSTEP(2); PSTEP(3);
    PSTEP(4); PSTEP(5); PSTEP(6); PSTEP(7);
    __builtin_amdgcn_sched_barrier(0);
    PREP(0, n0.x, n0.y); PREP(1, n0.z, n0.w);
    PREP(2, n1.x, n1.y); PREP(3, n1.z, n1.w);
    PREP(4, n2.x, n2.y); PREP(5, n2.z, n2.w);
    PREP(6, n3.x, n3.y); PREP(7, n3.z, n3.w);
    n0 = m0; n1 = m1; n2 = m2; n3 = m3;
  }
  // Epilogue: block 126 (in po/shv), then block 127 (PREP from n).
  PSTEP(0); PSTEP(1); PSTEP(2); PSTEP(3);
  PSTEP(4); PSTEP(5); PSTEP(6); PSTEP(7);
  PREP(0, n0.x, n0.y); PREP(1, n0.z, n0.w);
  PREP(2, n1.x, n1.y); PREP(3, n1.z, n1.w);
  PREP(4, n2.x, n2.y); PREP(5, n2.z, n2.w);
  PREP(6, n3.x, n3.y); PREP(7, n3.z, n3.w);
  PSTEP(0); PSTEP(1); PSTEP(2); PSTEP(3);
  PSTEP(4); PSTEP(5); PSTEP(6); PSTEP(7);
#undef PSTEP
#undef PREP

  // One-hot row write: 15 x float4 = 60 floats, fully overwrites output.
  float4* op = (float4*)(out + (size_t)row * NTOK);
#pragma unroll
  for (int j = 0; j < 15; ++j) {
    float4 v;
    v.x = ((uint32_t)(4 * j + 0) == s) ? 5.0f : 0.0f;
    v.y = ((uint32_t)(4 * j + 1) == s) ? 5.0f : 0.0f;
    v.z = ((uint32_t)(4 * j + 2) == s) ? 5.0f : 0.0f;
    v.w = ((uint32_t)(4 * j + 3) == s) ? 5.0f : 0.0f;
    op[j] = v;
  }
}

// ---------------- fallback: round-1 single-token chain ----------------------
__global__ __launch_bounds__(BROWS, 1) void a5_scan_kernel(
    const int* __restrict__ ids, const int* __restrict__ mul,
    float* __restrict__ out) {
  __shared__ uint32_t tab[NTOK * NTOK];
  const int lane = threadIdx.x;
  for (int i = lane; i < NTOK * NTOK; i += BROWS)
    tab[i] = ((uint32_t)mul[i]) << 2;
  __syncthreads();

  const int row = blockIdx.x * BROWS + lane;
  const int4* rp = (const int4*)(ids + (size_t)row * T_LEN);
  const char* tb = (const char*)tab;
  int4 c0 = rp[0], c1 = rp[1], c2 = rp[2], c3 = rp[3];
  uint32_t s4 = 0;
#define STEP(X)                                  \
  do {                                           \
    uint32_t base_ = (uint32_t)(X)*240u;         \
    s4 = *(const uint32_t*)(tb + base_ + s4);    \
  } while (0)
  for (int t = 0; t < T_LEN; t += 16) {
    int4 q0, q1, q2, q3;
    const bool more = (t + 16) < T_LEN;
    if (more) {
      const int4* np = rp + (t >> 2) + 4;
      q0 = np[0]; q1 = np[1]; q2 = np[2]; q3 = np[3];
    }
    STEP(c0.x); STEP(c0.y); STEP(c0.z); STEP(c0.w);
    STEP(c1.x); STEP(c1.y); STEP(c1.z); STEP(c1.w);
    STEP(c2.x); STEP(c2.y); STEP(c2.z); STEP(c2.w);
    STEP(c3.x); STEP(c3.y); STEP(c3.z); STEP(c3.w);
    if (more) { c0 = q0; c1 = q1; c2 = q2; c3 = q3; }
  }
#undef STEP
  const uint32_t s = s4 >> 2;
  float4* op = (float4*)(out + (size_t)row * NTOK);
#pragma unroll
  for (int j = 0; j < 15; ++j) {
    float4 v;
    v.x = ((uint32_t)(4 * j + 0) == s) ? 5.0f : 0.0f;
    v.y = ((uint32_t)(4 * j + 1) == s) ? 5.0f : 0.0f;
    v.z = ((uint32_t)(4 * j + 2) == s) ? 5.0f : 0.0f;
    v.w = ((uint32_t)(4 * j + 3) == s) ? 5.0f : 0.0f;
    op[j] = v;
  }
}

extern "C" void kernel_launch(void* const* d_in, const int* in_sizes, int n_in,
                              void* d_out, int out_size, void* d_ws,
                              size_t ws_size, hipStream_t stream) {
  const int* ids = (const int*)d_in[0];
  const int* mul = (const int*)d_in[1];
  float* out = (float*)d_out;
  const int B = in_sizes[0] / T_LEN;  // 16384
  const int grid = B / BROWS;         // 256 blocks

  if (ws_size >= (size_t)TAB_BYTES) {
    uint32_t* packed = (uint32_t*)d_ws;
    (void)hipFuncSetAttribute((const void*)a5_scan2_kernel,
                              hipFuncAttributeMaxDynamicSharedMemorySize,
                              TAB_BYTES);
    a5_build_kernel<<<(ALLOC_WORDS + 255) / 256, 256, 0, stream>>>(mul, packed);
    a5_scan2_kernel<<<grid, BROWS, TAB_BYTES, stream>>>(ids, packed, out);
  } else {
    a5_scan_kernel<<<grid, BROWS, 0, stream>>>(ids, mul, out);
  }
}